// Round 2
// baseline (294.177 us; speedup 1.0000x reference)
//
#include <hip/hip_runtime.h>

// Problem constants: N=4, C=320, H=W=D=16 -> L=4096, POS_RATIO=0.5
#define LVOX   4096
#define NCH    320
#define NCOMBO 8        // 4 batches x 2 branches (normal, batch-flipped q)
#define MAXCAP 131072   // fallback path: pairs per combo
#define CHUNKS 4

struct Geo {
    float qs0, qs1, qs2, qo0, qo1, qo2;
    float ks0, ks1, ks2, ko0, ko1, ko2;
    float ik0, ik1, ik2;
    float T;
};

// max_diag uses UNFLIPPED diag_q[n] even in flipped branch (computed pre-flip in ref).
__device__ __forceinline__ Geo make_geo(const float* __restrict__ cq,
                                        const float* __restrict__ ck,
                                        int n, int qb) {
    Geo g;
    const float* qc = cq + qb * 6;
    const float* qn = cq + n * 6;
    const float* kc = ck + n * 6;
    g.qs0 = (qc[3] - qc[0]) * (1.f / 16.f); g.qo0 = qc[0];
    g.qs1 = (qc[4] - qc[1]) * (1.f / 16.f); g.qo1 = qc[1];
    g.qs2 = (qc[5] - qc[2]) * (1.f / 16.f); g.qo2 = qc[2];
    g.ks0 = (kc[3] - kc[0]) * (1.f / 16.f); g.ko0 = kc[0];
    g.ks1 = (kc[4] - kc[1]) * (1.f / 16.f); g.ko1 = kc[1];
    g.ks2 = (kc[5] - kc[2]) * (1.f / 16.f); g.ko2 = kc[2];
    g.ik0 = 1.f / g.ks0; g.ik1 = 1.f / g.ks1; g.ik2 = 1.f / g.ks2;
    float b0 = (qn[3] - qn[0]) * (1.f / 16.f);
    float b1 = (qn[4] - qn[1]) * (1.f / 16.f);
    float b2 = (qn[5] - qn[2]) * (1.f / 16.f);
    float dq = sqrtf(b0 * b0 + b1 * b1 + b2 * b2);
    float dk = sqrtf(g.ks0 * g.ks0 + g.ks1 * g.ks1 + g.ks2 * g.ks2);
    g.T = 0.5f * fmaxf(dq, dk);
    return g;
}

__device__ __forceinline__ void axrange(float c, float ko, float ik, float T,
                                        int& m0, int& m1) {
    float lo = (c - T - ko) * ik - 0.5f;
    float hi = (c + T - ko) * ik - 0.5f;
    m0 = max((int)ceilf(lo) - 1, 0);
    m1 = min((int)floorf(hi) + 1, 15);
}

// ---------------- fast path: transpose to (n, l, c) then coalesced masked sum ---------

// (n, C, L) -> (n, L, C) tiled transpose for q and k. grid (L/32, C/32, 8), block (32,8).
__global__ void transpose_cl(const float* __restrict__ q, const float* __restrict__ k,
                             float* __restrict__ q_t, float* __restrict__ k_t) {
    __shared__ float tile[32][33];
    int z = blockIdx.z;
    int n = z & 3;
    const float* src = (z < 4 ? q : k) + (size_t)n * NCH * LVOX;
    float* dst = (z < 4 ? q_t : k_t) + (size_t)n * LVOX * NCH;
    int tx = threadIdx.x, ty = threadIdx.y;
    int c0 = blockIdx.y * 32;   // C block
    int l0 = blockIdx.x * 32;   // L block
#pragma unroll
    for (int i = 0; i < 4; ++i)
        tile[ty + 8 * i][tx] = src[(size_t)(c0 + ty + 8 * i) * LVOX + l0 + tx];
    __syncthreads();
#pragma unroll
    for (int i = 0; i < 4; ++i)
        dst[(size_t)(l0 + ty + 8 * i) * NCH + c0 + tx] = tile[tx][ty + 8 * i];
}

// One wave per (combo, l). Lanes = channels (c = lane + 64*i, 5 regs).
// acc_c = sum over masked m of k_t[n][m][c]; num = sum_c q_t[qb][l][c] * acc_c.
// Window membership is wave-uniform (identical scalar compute on all lanes).
__global__ void masked_sum(const float* __restrict__ q_t, const float* __restrict__ k_t,
                           const float* __restrict__ coord_q,
                           const float* __restrict__ coord_k,
                           float* __restrict__ S, unsigned* __restrict__ pcnt) {
    __shared__ float s_num[4];
    __shared__ unsigned s_cnt[4];
    int wv = threadIdx.x >> 6;
    int lane = threadIdx.x & 63;
    int wid = blockIdx.x * 4 + wv;       // 4 waves/block, block never straddles combos
    int j = wid >> 12;
    int l = wid & 4095;
    int n = j & 3;
    int qb = (j & 4) ? (3 - n) : n;
    Geo g = make_geo(coord_q, coord_k, n, qb);

    int ix = l >> 8, iy = (l >> 4) & 15, iz = l & 15;
    float cx = (ix + 0.5f) * g.qs0 + g.qo0;
    float cy = (iy + 0.5f) * g.qs1 + g.qo1;
    float cz = (iz + 0.5f) * g.qs2 + g.qo2;
    int x0, x1, y0, y1, z0, z1;
    axrange(cx, g.ko0, g.ik0, g.T, x0, x1);
    axrange(cy, g.ko1, g.ik1, g.T, y0, y1);
    axrange(cz, g.ko2, g.ik2, g.T, z0, z1);

    float a0 = 0.f, a1 = 0.f, a2 = 0.f, a3 = 0.f, a4 = 0.f;
    int nh = 0;
    for (int x = x0; x <= x1; ++x) {
        float dx = cx - ((x + 0.5f) * g.ks0 + g.ko0);
        float dx2 = dx * dx;
        for (int y = y0; y <= y1; ++y) {
            float dy = cy - ((y + 0.5f) * g.ks1 + g.ko1);
            float dxy = dx2 + dy * dy;
            for (int z = z0; z <= z1; ++z) {
                float dz = cz - ((z + 0.5f) * g.ks2 + g.ko2);
                if (sqrtf(dxy + dz * dz) < g.T) {
                    nh++;
                    int m = (x << 8) | (y << 4) | z;
                    const float* kr = k_t + ((size_t)(n * LVOX + m)) * NCH + lane;
                    a0 += kr[0];
                    a1 += kr[64];
                    a2 += kr[128];
                    a3 += kr[192];
                    a4 += kr[256];
                }
            }
        }
    }

    const float* qr = q_t + ((size_t)(qb * LVOX + l)) * NCH + lane;
    float num = a0 * qr[0] + a1 * qr[64] + a2 * qr[128] + a3 * qr[192] + a4 * qr[256];
#pragma unroll
    for (int off = 32; off; off >>= 1) num += __shfl_down(num, off, 64);

    if (lane == 0) { s_num[wv] = num; s_cnt[wv] = (unsigned)nh; }
    __syncthreads();
    if (threadIdx.x == 0) {
        float t = s_num[0] + s_num[1] + s_num[2] + s_num[3];
        unsigned ct = s_cnt[0] + s_cnt[1] + s_cnt[2] + s_cnt[3];
        atomicAdd(&S[j], t);
        atomicAdd(&pcnt[j], ct);
    }
}

// ---------------- fallback path (R1): pair list + channel-major gathers ----------------

__global__ void enum_pairs(const float* __restrict__ coord_q,
                           const float* __restrict__ coord_k,
                           unsigned* __restrict__ pcnt,
                           unsigned* __restrict__ pairs, int cap) {
    int gid = blockIdx.x * 256 + threadIdx.x;
    int j = gid >> 12;
    int l = gid & 4095;
    int n = j & 3;
    int qb = (j & 4) ? (3 - n) : n;
    Geo g = make_geo(coord_q, coord_k, n, qb);

    int ix = l >> 8, iy = (l >> 4) & 15, iz = l & 15;
    float cx = (ix + 0.5f) * g.qs0 + g.qo0;
    float cy = (iy + 0.5f) * g.qs1 + g.qo1;
    float cz = (iz + 0.5f) * g.qs2 + g.qo2;
    int x0, x1, y0, y1, z0, z1;
    axrange(cx, g.ko0, g.ik0, g.T, x0, x1);
    axrange(cy, g.ko1, g.ik1, g.T, y0, y1);
    axrange(cz, g.ko2, g.ik2, g.T, z0, z1);

    int nh = 0;
    for (int x = x0; x <= x1; ++x) {
        float dx = cx - ((x + 0.5f) * g.ks0 + g.ko0);
        float dx2 = dx * dx;
        for (int y = y0; y <= y1; ++y) {
            float dy = cy - ((y + 0.5f) * g.ks1 + g.ko1);
            float dxy = dx2 + dy * dy;
            for (int z = z0; z <= z1; ++z) {
                float dz = cz - ((z + 0.5f) * g.ks2 + g.ko2);
                if (sqrtf(dxy + dz * dz) < g.T) nh++;
            }
        }
    }

    int lane = threadIdx.x & 63;
    int incl = nh;
#pragma unroll
    for (int off = 1; off < 64; off <<= 1) {
        int t = __shfl_up(incl, off, 64);
        if (lane >= off) incl += t;
    }
    int total = __shfl(incl, 63, 64);
    int base = 0;
    if (lane == 63) base = (int)atomicAdd(&pcnt[j], (unsigned)total);
    base = __shfl(base, 63, 64);
    int w = base + incl - nh;

    unsigned* out = pairs + (size_t)j * (size_t)cap;
    for (int x = x0; x <= x1; ++x) {
        float dx = cx - ((x + 0.5f) * g.ks0 + g.ko0);
        float dx2 = dx * dx;
        for (int y = y0; y <= y1; ++y) {
            float dy = cy - ((y + 0.5f) * g.ks1 + g.ko1);
            float dxy = dx2 + dy * dy;
            for (int z = z0; z <= z1; ++z) {
                float dz = cz - ((z + 0.5f) * g.ks2 + g.ko2);
                if (sqrtf(dxy + dz * dz) < g.T) {
                    if (w < cap)
                        out[w] = ((unsigned)l << 12) | (unsigned)((x << 8) | (y << 4) | z);
                    w++;
                }
            }
        }
    }
}

__global__ void dot_pairs(const float* __restrict__ q, const float* __restrict__ k,
                          const unsigned* __restrict__ pcnt,
                          const unsigned* __restrict__ pairs, int cap,
                          float* __restrict__ S) {
    int wid = blockIdx.x * (blockDim.x >> 6) + (threadIdx.x >> 6);
    int lane = threadIdx.x & 63;
    int chunk = wid & (CHUNKS - 1);
    int rest = wid >> 2;
    int c = rest % NCH;
    int j = rest / NCH;
    if (j >= NCOMBO) return;
    int n = j & 3;
    int qb = (j & 4) ? (3 - n) : n;

    const float* qrow = q + ((size_t)(qb * NCH + c)) * LVOX;
    const float* krow = k + ((size_t)(n * NCH + c)) * LVOX;
    const unsigned* pl = pairs + (size_t)j * (size_t)cap;
    unsigned cnt = pcnt[j];
    if (cnt > (unsigned)cap) cnt = (unsigned)cap;

    float acc = 0.f;
    for (unsigned p = (unsigned)(chunk * 64 + lane); p < cnt; p += 64u * CHUNKS) {
        unsigned pr = pl[p];
        acc += qrow[pr >> 12] * krow[pr & 4095u];
    }
#pragma unroll
    for (int off = 32; off; off >>= 1) acc += __shfl_down(acc, off, 64);
    if (lane == 0) atomicAdd(&S[j], acc);
}

__global__ void finalize(const float* __restrict__ S,
                         const unsigned* __restrict__ pcnt,
                         float* __restrict__ out) {
    if (threadIdx.x == 0) {
        float t = 0.f;
#pragma unroll
        for (int j = 0; j < NCOMBO; ++j)
            t += S[j] / ((float)pcnt[j] + 1e-6f);
        out[0] = -0.5f * t;
    }
}

extern "C" void kernel_launch(void* const* d_in, const int* in_sizes, int n_in,
                              void* d_out, int out_size, void* d_ws, size_t ws_size,
                              hipStream_t stream) {
    const float* q       = (const float*)d_in[0];
    const float* k       = (const float*)d_in[1];
    const float* coord_q = (const float*)d_in[2];
    const float* coord_k = (const float*)d_in[3];
    float* out = (float*)d_out;

    float*    S    = (float*)d_ws;
    unsigned* pcnt = (unsigned*)d_ws + 8;

    const size_t elems = (size_t)4 * LVOX * NCH;          // one transposed array
    const size_t need  = 64 + 2 * elems * sizeof(float);  // ~42 MB

    hipMemsetAsync(d_ws, 0, 64, stream);

    if (ws_size >= need) {
        float* q_t = (float*)((char*)d_ws + 64);
        float* k_t = q_t + elems;
        dim3 tgrid(LVOX / 32, NCH / 32, 8);
        transpose_cl<<<tgrid, dim3(32, 8), 0, stream>>>(q, k, q_t, k_t);
        masked_sum<<<(NCOMBO * LVOX) / 4, 256, 0, stream>>>(q_t, k_t, coord_q, coord_k, S, pcnt);
    } else {
        unsigned* pairs = (unsigned*)d_ws + 16;
        size_t avail = (ws_size > 64) ? (ws_size / 4 - 16) / NCOMBO : 1;
        int cap = (int)((avail < (size_t)MAXCAP) ? avail : (size_t)MAXCAP);
        if (cap < 1) cap = 1;
        enum_pairs<<<(NCOMBO * LVOX) / 256, 256, 0, stream>>>(coord_q, coord_k, pcnt, pairs, cap);
        dot_pairs<<<(NCOMBO * NCH * CHUNKS) / 4, 256, 0, stream>>>(q, k, pcnt, pairs, cap, S);
    }
    finalize<<<1, 64, 0, stream>>>(S, pcnt, out);
}

// Round 3
// 144.142 us; speedup vs baseline: 2.0409x; 2.0409x over previous
//
#include <hip/hip_runtime.h>

// Problem constants: N=4, C=320, H=W=D=16 -> L=4096, POS_RATIO=0.5
#define LVOX   4096
#define NCH    320
#define NCOMBO 8        // 4 batches x 2 branches (normal, batch-flipped q)
#define PCAP   65536    // pairs per combo; math worst case ~53K (<=13 hits per l)

struct Geo {
    float qs0, qs1, qs2, qo0, qo1, qo2;
    float ks0, ks1, ks2, ko0, ko1, ko2;
    float ik0, ik1, ik2;
    float T;
};

// max_diag uses UNFLIPPED diag_q[n] even in the flipped branch (ref computes it pre-flip).
__device__ __forceinline__ Geo make_geo(const float* __restrict__ cq,
                                        const float* __restrict__ ck,
                                        int n, int qb) {
    Geo g;
    const float* qc = cq + qb * 6;
    const float* qn = cq + n * 6;
    const float* kc = ck + n * 6;
    g.qs0 = (qc[3] - qc[0]) * (1.f / 16.f); g.qo0 = qc[0];
    g.qs1 = (qc[4] - qc[1]) * (1.f / 16.f); g.qo1 = qc[1];
    g.qs2 = (qc[5] - qc[2]) * (1.f / 16.f); g.qo2 = qc[2];
    g.ks0 = (kc[3] - kc[0]) * (1.f / 16.f); g.ko0 = kc[0];
    g.ks1 = (kc[4] - kc[1]) * (1.f / 16.f); g.ko1 = kc[1];
    g.ks2 = (kc[5] - kc[2]) * (1.f / 16.f); g.ko2 = kc[2];
    g.ik0 = 1.f / g.ks0; g.ik1 = 1.f / g.ks1; g.ik2 = 1.f / g.ks2;
    float b0 = (qn[3] - qn[0]) * (1.f / 16.f);
    float b1 = (qn[4] - qn[1]) * (1.f / 16.f);
    float b2 = (qn[5] - qn[2]) * (1.f / 16.f);
    float dq = sqrtf(b0 * b0 + b1 * b1 + b2 * b2);
    float dk = sqrtf(g.ks0 * g.ks0 + g.ks1 * g.ks1 + g.ks2 * g.ks2);
    g.T = 0.5f * fmaxf(dq, dk);
    return g;
}

__device__ __forceinline__ void axrange(float c, float ko, float ik, float T,
                                        int& m0, int& m1) {
    float lo = (c - T - ko) * ik - 0.5f;
    float hi = (c + T - ko) * ik - 0.5f;
    m0 = max((int)ceilf(lo) - 1, 0);
    m1 = min((int)floorf(hi) + 1, 15);
}

// One THREAD per (combo, l): scans its candidate window once (scalar work not
// duplicated across a wave), emits CSR pair list per combo via wave-aggregated
// prefix-sum reservation. Also accumulates mask count pcnt[j].
__global__ void enum_pairs(const float* __restrict__ coord_q,
                           const float* __restrict__ coord_k,
                           unsigned* __restrict__ pcnt,
                           unsigned* __restrict__ pairs, int cap) {
    int gid = blockIdx.x * 256 + threadIdx.x;   // 8*4096 threads
    int j = gid >> 12;
    int l = gid & 4095;
    int n = j & 3;
    int qb = (j & 4) ? (3 - n) : n;
    Geo g = make_geo(coord_q, coord_k, n, qb);

    int ix = l >> 8, iy = (l >> 4) & 15, iz = l & 15;
    float cx = (ix + 0.5f) * g.qs0 + g.qo0;
    float cy = (iy + 0.5f) * g.qs1 + g.qo1;
    float cz = (iz + 0.5f) * g.qs2 + g.qo2;
    int x0, x1, y0, y1, z0, z1;
    axrange(cx, g.ko0, g.ik0, g.T, x0, x1);
    axrange(cy, g.ko1, g.ik1, g.T, y0, y1);
    axrange(cz, g.ko2, g.ik2, g.T, z0, z1);

    // pass 1: count
    int nh = 0;
    for (int x = x0; x <= x1; ++x) {
        float dx = cx - ((x + 0.5f) * g.ks0 + g.ko0);
        float dx2 = dx * dx;
        for (int y = y0; y <= y1; ++y) {
            float dy = cy - ((y + 0.5f) * g.ks1 + g.ko1);
            float dxy = dx2 + dy * dy;
            for (int z = z0; z <= z1; ++z) {
                float dz = cz - ((z + 0.5f) * g.ks2 + g.ko2);
                if (sqrtf(dxy + dz * dz) < g.T) nh++;
            }
        }
    }

    // wave-aggregated reservation (wave is uniform in j: 4096 % 64 == 0)
    int lane = threadIdx.x & 63;
    int incl = nh;
#pragma unroll
    for (int off = 1; off < 64; off <<= 1) {
        int t = __shfl_up(incl, off, 64);
        if (lane >= off) incl += t;
    }
    int total = __shfl(incl, 63, 64);
    int base = 0;
    if (lane == 63) base = (int)atomicAdd(&pcnt[j], (unsigned)total);
    base = __shfl(base, 63, 64);
    int w = base + incl - nh;

    // pass 2: write pairs (packed (l<<12)|m)
    unsigned* out = pairs + (size_t)j * (size_t)cap;
    for (int x = x0; x <= x1; ++x) {
        float dx = cx - ((x + 0.5f) * g.ks0 + g.ko0);
        float dx2 = dx * dx;
        for (int y = y0; y <= y1; ++y) {
            float dy = cy - ((y + 0.5f) * g.ks1 + g.ko1);
            float dxy = dx2 + dy * dy;
            for (int z = z0; z <= z1; ++z) {
                float dz = cz - ((z + 0.5f) * g.ks2 + g.ko2);
                if (sqrtf(dxy + dz * dz) < g.T) {
                    if (w < cap)
                        out[w] = ((unsigned)l << 12) | (unsigned)((x << 8) | (y << 4) | z);
                    w++;
                }
            }
        }
    }
}

// One block per (combo j, channel c): stage q[qb,c,:] and k[n,c,:] (16KB each)
// into LDS with coalesced float4 loads, then stride the combo's pair list doing
// LDS-resident gathers. Global access is 100% streaming; random access is LDS.
__global__ void __launch_bounds__(256) gather_lds(
        const float* __restrict__ q, const float* __restrict__ k,
        const unsigned* __restrict__ pcnt, const unsigned* __restrict__ pairs,
        int cap, float* __restrict__ S) {
    __shared__ float qrow[LVOX];
    __shared__ float krow[LVOX];
    __shared__ float sp[4];
    int j = blockIdx.x;          // grid.x = 8 (j fastest -> same-c blocks adjacent
    int c = blockIdx.y;          //  in dispatch order for k/q L2/L3 reuse)
    int n = j & 3;
    int qb = (j & 4) ? (3 - n) : n;
    const float* qsrc = q + ((size_t)(qb * NCH + c)) * LVOX;
    const float* ksrc = k + ((size_t)(n * NCH + c)) * LVOX;
    int t = threadIdx.x;

#pragma unroll
    for (int i = 0; i < 4; ++i) {
        int off = (t + 256 * i) * 4;
        *(float4*)&qrow[off] = *(const float4*)&qsrc[off];
        *(float4*)&krow[off] = *(const float4*)&ksrc[off];
    }
    __syncthreads();

    unsigned cnt = pcnt[j];
    if (cnt > (unsigned)cap) cnt = (unsigned)cap;
    const unsigned* pl = pairs + (size_t)j * (size_t)cap;

    float acc = 0.f;
    for (unsigned p = (unsigned)t; p < cnt; p += 256u) {
        unsigned pr = pl[p];
        acc += qrow[pr >> 12] * krow[pr & 4095u];
    }

#pragma unroll
    for (int off = 32; off; off >>= 1) acc += __shfl_down(acc, off, 64);
    int lane = t & 63;
    if (lane == 0) sp[t >> 6] = acc;
    __syncthreads();
    if (t == 0) atomicAdd(&S[j], sp[0] + sp[1] + sp[2] + sp[3]);
}

__global__ void finalize(const float* __restrict__ S,
                         const unsigned* __restrict__ pcnt,
                         float* __restrict__ out) {
    if (threadIdx.x == 0) {
        float t = 0.f;
#pragma unroll
        for (int j = 0; j < NCOMBO; ++j)
            t += S[j] / ((float)pcnt[j] + 1e-6f);
        out[0] = -0.5f * t;   // -2*mean over 4 batches, x2 branches
    }
}

extern "C" void kernel_launch(void* const* d_in, const int* in_sizes, int n_in,
                              void* d_out, int out_size, void* d_ws, size_t ws_size,
                              hipStream_t stream) {
    const float* q       = (const float*)d_in[0];
    const float* k       = (const float*)d_in[1];
    const float* coord_q = (const float*)d_in[2];
    const float* coord_k = (const float*)d_in[3];
    float* out = (float*)d_out;

    float*    S     = (float*)d_ws;          // 8 floats
    unsigned* pcnt  = (unsigned*)d_ws + 8;   // 8 uints
    unsigned* pairs = (unsigned*)d_ws + 16;

    size_t avail = (ws_size > 64) ? (ws_size / 4 - 16) / NCOMBO : 1;
    int cap = (int)((avail < (size_t)PCAP) ? avail : (size_t)PCAP);
    if (cap < 1) cap = 1;

    hipMemsetAsync(d_ws, 0, 64, stream);
    enum_pairs<<<(NCOMBO * LVOX) / 256, 256, 0, stream>>>(coord_q, coord_k, pcnt, pairs, cap);
    gather_lds<<<dim3(NCOMBO, NCH), 256, 0, stream>>>(q, k, pcnt, pairs, cap, S);
    finalize<<<1, 64, 0, stream>>>(S, pcnt, out);
}

// Round 4
// 139.134 us; speedup vs baseline: 2.1143x; 1.0360x over previous
//
#include <hip/hip_runtime.h>

// Problem constants: N=4, C=320, H=W=D=16 -> L=4096, POS_RATIO=0.5
#define LVOX   4096
#define NCH    320
#define NCOMBO 8        // 4 batches x 2 branches (normal, batch-flipped q)
#define RCAP   49152    // runs per combo; realistic worst ~37K (<=9 xy-cells per l)

struct Geo {
    float qs0, qs1, qs2, qo0, qo1, qo2;
    float ks0, ks1, ks2, ko0, ko1, ko2;
    float ik0, ik1, ik2;
    float T;
};

// max_diag uses UNFLIPPED diag_q[n] even in the flipped branch (ref computes it pre-flip).
__device__ __forceinline__ Geo make_geo(const float* __restrict__ cq,
                                        const float* __restrict__ ck,
                                        int n, int qb) {
    Geo g;
    const float* qc = cq + qb * 6;
    const float* qn = cq + n * 6;
    const float* kc = ck + n * 6;
    g.qs0 = (qc[3] - qc[0]) * (1.f / 16.f); g.qo0 = qc[0];
    g.qs1 = (qc[4] - qc[1]) * (1.f / 16.f); g.qo1 = qc[1];
    g.qs2 = (qc[5] - qc[2]) * (1.f / 16.f); g.qo2 = qc[2];
    g.ks0 = (kc[3] - kc[0]) * (1.f / 16.f); g.ko0 = kc[0];
    g.ks1 = (kc[4] - kc[1]) * (1.f / 16.f); g.ko1 = kc[1];
    g.ks2 = (kc[5] - kc[2]) * (1.f / 16.f); g.ko2 = kc[2];
    g.ik0 = 1.f / g.ks0; g.ik1 = 1.f / g.ks1; g.ik2 = 1.f / g.ks2;
    float b0 = (qn[3] - qn[0]) * (1.f / 16.f);
    float b1 = (qn[4] - qn[1]) * (1.f / 16.f);
    float b2 = (qn[5] - qn[2]) * (1.f / 16.f);
    float dq = sqrtf(b0 * b0 + b1 * b1 + b2 * b2);
    float dk = sqrtf(g.ks0 * g.ks0 + g.ks1 * g.ks1 + g.ks2 * g.ks2);
    g.T = 0.5f * fmaxf(dq, dk);
    return g;
}

__device__ __forceinline__ void axrange(float c, float ko, float ik, float T,
                                        int& m0, int& m1) {
    float lo = (c - T - ko) * ik - 0.5f;
    float hi = (c + T - ko) * ik - 0.5f;
    m0 = max((int)ceilf(lo) - 1, 0);
    m1 = min((int)floorf(hi) + 1, 15);
}

// One THREAD per (combo, l). For fixed (x,y), masked z's are a contiguous interval
// (dist^2 unimodal in z), so emit one RUN per (x,y) cell:
//   record = (l<<16) | (m_base<<4) | (len-1),  m_base = (x<<8)|(y<<4)|z_first
// Exact per-z sqrtf(...)<T test kept -> mask is bit-identical to the reference.
// rcnt[j] counts runs (list length); pcnt[j] counts hits (mask denominator).
__global__ void enum_runs(const float* __restrict__ coord_q,
                          const float* __restrict__ coord_k,
                          unsigned* __restrict__ pcnt,
                          unsigned* __restrict__ rcnt,
                          unsigned* __restrict__ runs, int cap) {
    int gid = blockIdx.x * 256 + threadIdx.x;   // 8*4096 threads
    int j = gid >> 12;
    int l = gid & 4095;
    int n = j & 3;
    int qb = (j & 4) ? (3 - n) : n;
    Geo g = make_geo(coord_q, coord_k, n, qb);

    int ix = l >> 8, iy = (l >> 4) & 15, iz = l & 15;
    float cx = (ix + 0.5f) * g.qs0 + g.qo0;
    float cy = (iy + 0.5f) * g.qs1 + g.qo1;
    float cz = (iz + 0.5f) * g.qs2 + g.qo2;
    int x0, x1, y0, y1, z0, z1;
    axrange(cx, g.ko0, g.ik0, g.T, x0, x1);
    axrange(cy, g.ko1, g.ik1, g.T, y0, y1);
    axrange(cz, g.ko2, g.ik2, g.T, z0, z1);

    // pass 1: count runs and hits
    int nh = 0, nr = 0;
    for (int x = x0; x <= x1; ++x) {
        float dx = cx - ((x + 0.5f) * g.ks0 + g.ko0);
        float dx2 = dx * dx;
        for (int y = y0; y <= y1; ++y) {
            float dy = cy - ((y + 0.5f) * g.ks1 + g.ko1);
            float dxy = dx2 + dy * dy;
            int zc = 0;
            for (int z = z0; z <= z1; ++z) {
                float dz = cz - ((z + 0.5f) * g.ks2 + g.ko2);
                if (sqrtf(dxy + dz * dz) < g.T) zc++;
            }
            if (zc) { nr++; nh += zc; }
        }
    }

    // wave-aggregated reservation over run counts (wave uniform in j: 4096%64==0)
    int lane = threadIdx.x & 63;
    int incl = nr;
#pragma unroll
    for (int off = 1; off < 64; off <<= 1) {
        int t = __shfl_up(incl, off, 64);
        if (lane >= off) incl += t;
    }
    int total = __shfl(incl, 63, 64);
    int base = 0;
    if (lane == 63) base = (int)atomicAdd(&rcnt[j], (unsigned)total);
    base = __shfl(base, 63, 64);
    int w = base + incl - nr;

    // hit count: one atomic per wave
    int hsum = nh;
#pragma unroll
    for (int off = 32; off; off >>= 1) hsum += __shfl_down(hsum, off, 64);
    if (lane == 0) atomicAdd(&pcnt[j], (unsigned)hsum);

    // pass 2: write runs
    unsigned* out = runs + (size_t)j * (size_t)cap;
    for (int x = x0; x <= x1; ++x) {
        float dx = cx - ((x + 0.5f) * g.ks0 + g.ko0);
        float dx2 = dx * dx;
        for (int y = y0; y <= y1; ++y) {
            float dy = cy - ((y + 0.5f) * g.ks1 + g.ko1);
            float dxy = dx2 + dy * dy;
            int zf = -1, zc = 0;
            for (int z = z0; z <= z1; ++z) {
                float dz = cz - ((z + 0.5f) * g.ks2 + g.ko2);
                if (sqrtf(dxy + dz * dz) < g.T) { if (!zc) zf = z; zc++; }
            }
            if (zc) {
                if (w < cap)
                    out[w] = ((unsigned)l << 16)
                           | ((unsigned)((x << 8) | (y << 4) | zf) << 4)
                           | (unsigned)(zc - 1);
                w++;
            }
        }
    }
}

// One block per (combo j, channel c): stage q[qb,c,:], k[n,c,:] into LDS, then
// stride the combo's RUN list 4-at-a-time (uint4). Per run: contiguous krow
// reads (LDS), one qrow read, FMA. 512 thr -> 8 waves, LDS 33KB -> 4 blk/CU.
__global__ void __launch_bounds__(512) gather_runs(
        const float* __restrict__ q, const float* __restrict__ k,
        const unsigned* __restrict__ rcnt, const unsigned* __restrict__ runs,
        int cap, float* __restrict__ S) {
    __shared__ float qrow[LVOX];
    __shared__ float krow[LVOX + 16];   // +16: masked garbage decode stays in-bounds
    __shared__ float sp[8];
    int j = blockIdx.x;          // j fastest -> same-c blocks adjacent for L2/L3 reuse
    int c = blockIdx.y;
    int n = j & 3;
    int qb = (j & 4) ? (3 - n) : n;
    const float* qsrc = q + ((size_t)(qb * NCH + c)) * LVOX;
    const float* ksrc = k + ((size_t)(n * NCH + c)) * LVOX;
    int t = threadIdx.x;

#pragma unroll
    for (int i = 0; i < 2; ++i) {
        int off = (t + 512 * i) * 4;
        *(float4*)&qrow[off] = *(const float4*)&qsrc[off];
        *(float4*)&krow[off] = *(const float4*)&ksrc[off];
    }
    if (t < 4) krow[LVOX + 4 * t] = 0.f;  // zero the pad region (not strictly needed)
    __syncthreads();

    unsigned cnt = rcnt[j];
    if (cnt > (unsigned)cap) cnt = (unsigned)cap;
    const unsigned* rl = runs + (size_t)j * (size_t)cap;

    float acc = 0.f;
    // p aligned to 4; cap%4==0 so p+3 < cap always (no OOB on the uint4 load)
    for (unsigned p = (unsigned)t * 4u; p < cnt; p += 512u * 4u) {
        uint4 r4 = *(const uint4*)&rl[p];
        unsigned rr[4] = {r4.x, r4.y, r4.z, r4.w};
#pragma unroll
        for (int e = 0; e < 4; ++e) {
            bool valid = (p + (unsigned)e) < cnt;
            unsigned pr = rr[e];
            int l  = (int)(pr >> 16) & 4095;
            int mb = (int)(pr >> 4) & 4095;
            int len = (int)(pr & 15u) + 1;
            float s = 0.f;
            for (int i = 0; i < len; ++i) s += krow[mb + i];
            acc += valid ? (qrow[l] * s) : 0.f;
        }
    }

#pragma unroll
    for (int off = 32; off; off >>= 1) acc += __shfl_down(acc, off, 64);
    int lane = t & 63;
    if (lane == 0) sp[t >> 6] = acc;
    __syncthreads();
    if (t == 0) {
        float v = 0.f;
#pragma unroll
        for (int i = 0; i < 8; ++i) v += sp[i];
        atomicAdd(&S[j], v);
    }
}

__global__ void finalize(const float* __restrict__ S,
                         const unsigned* __restrict__ pcnt,
                         float* __restrict__ out) {
    if (threadIdx.x == 0) {
        float t = 0.f;
#pragma unroll
        for (int j = 0; j < NCOMBO; ++j)
            t += S[j] / ((float)pcnt[j] + 1e-6f);
        out[0] = -0.5f * t;   // -2*mean over 4 batches, x2 branches
    }
}

extern "C" void kernel_launch(void* const* d_in, const int* in_sizes, int n_in,
                              void* d_out, int out_size, void* d_ws, size_t ws_size,
                              hipStream_t stream) {
    const float* q       = (const float*)d_in[0];
    const float* k       = (const float*)d_in[1];
    const float* coord_q = (const float*)d_in[2];
    const float* coord_k = (const float*)d_in[3];
    float* out = (float*)d_out;

    // ws layout: S[8] f32 | pcnt[8] u32 | rcnt[8] u32 | pad to 128B | runs[8*cap]
    float*    S    = (float*)d_ws;
    unsigned* pcnt = (unsigned*)d_ws + 8;
    unsigned* rcnt = (unsigned*)d_ws + 16;
    unsigned* runs = (unsigned*)((char*)d_ws + 128);

    size_t avail = (ws_size > 128) ? ((ws_size - 128) / 4) / NCOMBO : 4;
    avail &= ~(size_t)3;                                  // keep cap % 4 == 0
    int cap = (int)((avail < (size_t)RCAP) ? avail : (size_t)RCAP);
    if (cap < 4) cap = 4;

    hipMemsetAsync(d_ws, 0, 128, stream);
    enum_runs<<<(NCOMBO * LVOX) / 256, 256, 0, stream>>>(coord_q, coord_k, pcnt, rcnt, runs, cap);
    gather_runs<<<dim3(NCOMBO, NCH), 512, 0, stream>>>(q, k, rcnt, runs, cap, S);
    finalize<<<1, 64, 0, stream>>>(S, pcnt, out);
}

// Round 5
// 125.028 us; speedup vs baseline: 2.3529x; 1.1128x over previous
//
#include <hip/hip_runtime.h>

// Problem constants: N=4, C=320, H=W=D=16 -> L=4096, POS_RATIO=0.5
#define LVOX   4096
#define NCH    320
#define NCOMBO 8        // 4 batches x 2 branches (normal, batch-flipped q)
#define RCAP   49152    // runs per combo; realistic worst ~37K
#define PKSTR  17       // prefix-sum entries per (x,y) cell (exclusive, 0..16)
#define PKROW  (256 * PKSTR)
#define NBLK   (2 * NCH)        // gather blocks = 640
#define SPART_OFF 128           // byte offset of Spart[8][NBLK] in ws
#define RUNS_OFF  (SPART_OFF + NCOMBO * NBLK * 4)   // 20608, 16B aligned

struct Geo {
    float qs0, qs1, qs2, qo0, qo1, qo2;
    float ks0, ks1, ks2, ko0, ko1, ko2;
    float ik0, ik1, ik2;
    float T;
};

// max_diag uses UNFLIPPED diag_q[n] even in the flipped branch (ref computes it pre-flip).
__device__ __forceinline__ Geo make_geo(const float* __restrict__ cq,
                                        const float* __restrict__ ck,
                                        int n, int qb) {
    Geo g;
    const float* qc = cq + qb * 6;
    const float* qn = cq + n * 6;
    const float* kc = ck + n * 6;
    g.qs0 = (qc[3] - qc[0]) * (1.f / 16.f); g.qo0 = qc[0];
    g.qs1 = (qc[4] - qc[1]) * (1.f / 16.f); g.qo1 = qc[1];
    g.qs2 = (qc[5] - qc[2]) * (1.f / 16.f); g.qo2 = qc[2];
    g.ks0 = (kc[3] - kc[0]) * (1.f / 16.f); g.ko0 = kc[0];
    g.ks1 = (kc[4] - kc[1]) * (1.f / 16.f); g.ko1 = kc[1];
    g.ks2 = (kc[5] - kc[2]) * (1.f / 16.f); g.ko2 = kc[2];
    g.ik0 = 1.f / g.ks0; g.ik1 = 1.f / g.ks1; g.ik2 = 1.f / g.ks2;
    float b0 = (qn[3] - qn[0]) * (1.f / 16.f);
    float b1 = (qn[4] - qn[1]) * (1.f / 16.f);
    float b2 = (qn[5] - qn[2]) * (1.f / 16.f);
    float dq = sqrtf(b0 * b0 + b1 * b1 + b2 * b2);
    float dk = sqrtf(g.ks0 * g.ks0 + g.ks1 * g.ks1 + g.ks2 * g.ks2);
    g.T = 0.5f * fmaxf(dq, dk);
    return g;
}

__device__ __forceinline__ void axrange(float c, float ko, float ik, float T,
                                        int& m0, int& m1) {
    float lo = (c - T - ko) * ik - 0.5f;
    float hi = (c + T - ko) * ik - 0.5f;
    m0 = max((int)ceilf(lo) - 1, 0);
    m1 = min((int)floorf(hi) + 1, 15);
}

// One THREAD per (combo, l); emits one RUN per masked (x,y) cell:
//   record = (l<<16) | (m<<4) | (len-1),  m = (x<<8)|(y<<4)|z_first
// Exact per-z sqrtf(...)<T test -> mask identical to reference.
__global__ void enum_runs(const float* __restrict__ coord_q,
                          const float* __restrict__ coord_k,
                          unsigned* __restrict__ pcnt,
                          unsigned* __restrict__ rcnt,
                          unsigned* __restrict__ runs, int cap) {
    int gid = blockIdx.x * 256 + threadIdx.x;   // 8*4096 threads
    int j = gid >> 12;
    int l = gid & 4095;
    int n = j & 3;
    int qb = (j & 4) ? (3 - n) : n;
    Geo g = make_geo(coord_q, coord_k, n, qb);

    int ix = l >> 8, iy = (l >> 4) & 15, iz = l & 15;
    float cx = (ix + 0.5f) * g.qs0 + g.qo0;
    float cy = (iy + 0.5f) * g.qs1 + g.qo1;
    float cz = (iz + 0.5f) * g.qs2 + g.qo2;
    int x0, x1, y0, y1, z0, z1;
    axrange(cx, g.ko0, g.ik0, g.T, x0, x1);
    axrange(cy, g.ko1, g.ik1, g.T, y0, y1);
    axrange(cz, g.ko2, g.ik2, g.T, z0, z1);

    int nh = 0, nr = 0;
    for (int x = x0; x <= x1; ++x) {
        float dx = cx - ((x + 0.5f) * g.ks0 + g.ko0);
        float dx2 = dx * dx;
        for (int y = y0; y <= y1; ++y) {
            float dy = cy - ((y + 0.5f) * g.ks1 + g.ko1);
            float dxy = dx2 + dy * dy;
            int zc = 0;
            for (int z = z0; z <= z1; ++z) {
                float dz = cz - ((z + 0.5f) * g.ks2 + g.ko2);
                if (sqrtf(dxy + dz * dz) < g.T) zc++;
            }
            if (zc) { nr++; nh += zc; }
        }
    }

    int lane = threadIdx.x & 63;
    int incl = nr;
#pragma unroll
    for (int off = 1; off < 64; off <<= 1) {
        int t = __shfl_up(incl, off, 64);
        if (lane >= off) incl += t;
    }
    int total = __shfl(incl, 63, 64);
    int base = 0;
    if (lane == 63) base = (int)atomicAdd(&rcnt[j], (unsigned)total);
    base = __shfl(base, 63, 64);
    int w = base + incl - nr;

    int hsum = nh;
#pragma unroll
    for (int off = 32; off; off >>= 1) hsum += __shfl_down(hsum, off, 64);
    if (lane == 0) atomicAdd(&pcnt[j], (unsigned)hsum);

    unsigned* out = runs + (size_t)j * (size_t)cap;
    for (int x = x0; x <= x1; ++x) {
        float dx = cx - ((x + 0.5f) * g.ks0 + g.ko0);
        float dx2 = dx * dx;
        for (int y = y0; y <= y1; ++y) {
            float dy = cy - ((y + 0.5f) * g.ks1 + g.ko1);
            float dxy = dx2 + dy * dy;
            int zf = -1, zc = 0;
            for (int z = z0; z <= z1; ++z) {
                float dz = cz - ((z + 0.5f) * g.ks2 + g.ko2);
                if (sqrtf(dxy + dz * dz) < g.T) { if (!zc) zf = z; zc++; }
            }
            if (zc) {
                if (w < cap)
                    out[w] = ((unsigned)l << 16)
                           | ((unsigned)((x << 8) | (y << 4) | zf) << 4)
                           | (unsigned)(zc - 1);
                w++;
            }
        }
    }
}

// Fused gather: one block per (group g, channel c). Group g=0 -> batches {0,3},
// g=1 -> {1,2}; combos {n0, n1, 4+n0, 4+n1} form a closed set over rows
// {q[n0,c], q[n1,c], k[n0,c], k[n1,c]} -> each row staged ONCE globally.
// k rows stored as per-(x,y)-cell exclusive z-prefix sums (stride 17,
// bank-conflict-free): run sum = pk[zf+len] - pk[zf]. No contended atomics:
// per-block partial sums land in Spart[j][block].
__global__ void __launch_bounds__(512) gather_fused(
        const float* __restrict__ q, const float* __restrict__ k,
        const unsigned* __restrict__ rcnt, const unsigned* __restrict__ runs,
        int cap, float* __restrict__ Spart) {
    // sh layout: qa[4096] | qb[4096] | pkA[PKROW] | pkB[PKROW] | sred[32]
    __shared__ float sh[2 * LVOX + 2 * PKROW + 32];
    const int QA = 0, QB = LVOX, PK = 2 * LVOX, SR = 2 * LVOX + 2 * PKROW;

    int g = blockIdx.x;              // 0 or 1
    int c = blockIdx.y;
    int n0 = g ? 1 : 0;
    int n1 = 3 - n0;
    int t = threadIdx.x;

    // stage q rows (coalesced float4)
    const float* q0 = q + ((size_t)(n0 * NCH + c)) * LVOX;
    const float* q1 = q + ((size_t)(n1 * NCH + c)) * LVOX;
#pragma unroll
    for (int i = 0; i < 2; ++i) {
        int off = (t + 512 * i) * 4;
        *(float4*)&sh[QA + off] = *(const float4*)&q0[off];
        *(float4*)&sh[QB + off] = *(const float4*)&q1[off];
    }

    // stage k rows as exclusive z-prefix per cell: thread t owns one cell
    {
        int row = t >> 8;            // 0 -> k[n0], 1 -> k[n1]
        int cl  = t & 255;
        const float* ks = k + ((size_t)((row ? n1 : n0) * NCH + c)) * LVOX + cl * 16;
        float4 v0 = *(const float4*)&ks[0];
        float4 v1 = *(const float4*)&ks[4];
        float4 v2 = *(const float4*)&ks[8];
        float4 v3 = *(const float4*)&ks[12];
        float vv[16] = {v0.x, v0.y, v0.z, v0.w, v1.x, v1.y, v1.z, v1.w,
                        v2.x, v2.y, v2.z, v2.w, v3.x, v3.y, v3.z, v3.w};
        float* dst = &sh[PK + row * PKROW + cl * PKSTR];
        float e = 0.f;
        dst[0] = 0.f;
#pragma unroll
        for (int i = 0; i < 16; ++i) { e += vv[i]; dst[i + 1] = e; }
    }
    __syncthreads();

    const int jl[4]   = {n0, n1, 4 + n0, 4 + n1};
    const int qoff[4] = {QA, QB, QB, QA};              // combo 4+n uses q[3-n]
    const int koff[4] = {PK, PK + PKROW, PK, PK + PKROW};
    float accv[4];

#pragma unroll
    for (int ci = 0; ci < 4; ++ci) {
        int j = jl[ci];
        unsigned cnt = rcnt[j];
        if (cnt > (unsigned)cap) cnt = (unsigned)cap;
        const unsigned* rl = runs + (size_t)j * (size_t)cap;
        int qb = qoff[ci], kb = koff[ci];
        float acc = 0.f;
        for (unsigned p = (unsigned)t * 4u; p < cnt; p += 512u * 4u) {
            uint4 r4 = *(const uint4*)&rl[p];   // cap%4==0 -> in-bounds
            unsigned rr[4] = {r4.x, r4.y, r4.z, r4.w};
#pragma unroll
            for (int e = 0; e < 4; ++e) {
                bool valid = (p + (unsigned)e) < cnt;
                unsigned pr = rr[e];
                int l    = (int)(pr >> 16);
                int cell = (int)((pr >> 8) & 255u);
                int zf   = (int)((pr >> 4) & 15u);
                int len  = (int)(pr & 15u) + 1;
                float s = sh[kb + cell * PKSTR + zf + len] - sh[kb + cell * PKSTR + zf];
                acc += valid ? sh[qb + l] * s : 0.f;
            }
        }
        accv[ci] = acc;
    }

    int wv = t >> 6, lane = t & 63;
#pragma unroll
    for (int ci = 0; ci < 4; ++ci) {
        float a = accv[ci];
#pragma unroll
        for (int off = 32; off; off >>= 1) a += __shfl_down(a, off, 64);
        if (lane == 0) sh[SR + wv * 4 + ci] = a;
    }
    __syncthreads();
    if (t < 4) {
        float v = 0.f;
#pragma unroll
        for (int w = 0; w < 8; ++w) v += sh[SR + w * 4 + t];
        Spart[(size_t)jl[t] * NBLK + (c * 2 + g)] = v;
    }
}

// Sum Spart over each combo's 320 blocks, divide by mask count, combine.
__global__ void finalize(const float* __restrict__ Spart,
                         const unsigned* __restrict__ pcnt,
                         float* __restrict__ out) {
    __shared__ float tj[NCOMBO];
    int j = threadIdx.x >> 5;      // 8 combos x 32 threads
    int s = threadIdx.x & 31;
    int nn = j & 3;
    int gj = (nn == 1 || nn == 2) ? 1 : 0;
    float v = 0.f;
    for (int i = s; i < NCH; i += 32)
        v += Spart[(size_t)j * NBLK + i * 2 + gj];
#pragma unroll
    for (int off = 16; off; off >>= 1) v += __shfl_down(v, off, 32);
    if (s == 0) tj[j] = v;
    __syncthreads();
    if (threadIdx.x == 0) {
        float t = 0.f;
#pragma unroll
        for (int jj = 0; jj < NCOMBO; ++jj)
            t += tj[jj] / ((float)pcnt[jj] + 1e-6f);
        out[0] = -0.5f * t;   // -2*mean over 4 batches, x2 branches
    }
}

extern "C" void kernel_launch(void* const* d_in, const int* in_sizes, int n_in,
                              void* d_out, int out_size, void* d_ws, size_t ws_size,
                              hipStream_t stream) {
    const float* q       = (const float*)d_in[0];
    const float* k       = (const float*)d_in[1];
    const float* coord_q = (const float*)d_in[2];
    const float* coord_k = (const float*)d_in[3];
    float* out = (float*)d_out;

    // ws: [pcnt[8] u32 | rcnt[8] u32 | pad to 128] [Spart 8*640 f32] [runs 8*cap u32]
    unsigned* pcnt  = (unsigned*)d_ws;
    unsigned* rcnt  = (unsigned*)d_ws + 8;
    float*    Spart = (float*)((char*)d_ws + SPART_OFF);
    unsigned* runs  = (unsigned*)((char*)d_ws + RUNS_OFF);

    size_t avail = (ws_size > RUNS_OFF) ? ((ws_size - RUNS_OFF) / 4) / NCOMBO : 4;
    avail &= ~(size_t)3;                                  // cap % 4 == 0
    int cap = (int)((avail < (size_t)RCAP) ? avail : (size_t)RCAP);
    if (cap < 4) cap = 4;

    hipMemsetAsync(d_ws, 0, 128, stream);   // pcnt/rcnt only; Spart fully overwritten
    enum_runs<<<(NCOMBO * LVOX) / 256, 256, 0, stream>>>(coord_q, coord_k, pcnt, rcnt, runs, cap);
    gather_fused<<<dim3(2, NCH), 512, 0, stream>>>(q, k, rcnt, runs, cap, Spart);
    finalize<<<1, 256, 0, stream>>>(Spart, pcnt, out);
}